// Round 5
// baseline (1044.339 us; speedup 1.0000x reference)
//
#include <hip/hip_runtime.h>
#include <hip/hip_bf16.h>
#include <hip/hip_fp16.h>

typedef unsigned short ushortT;
typedef _Float16 half8 __attribute__((ext_vector_type(8)));
typedef float f32x4 __attribute__((ext_vector_type(4)));

#define N_ROWS   32768
#define DIM      512
#define K_CODES  8192
#define BETA     0.01f

// d_out layout (floats): [quantized 16777216][loss 1][indices-as-float 32768]
#define LOSS_OFF 16777216
#define IDX_OFF  16777217

// d_out-as-scratch (floats offsets). Legal: vq_gather rewrites [0,16.7M) last.
#define SC_XH_F    0            // 32768*512 halves = 8M floats
#define SC_EH_F    8388608      // 8192*512 halves  = 2M floats
#define SC_GCODE_F 10485760     // 32768*16 u32
#define SC_GCNT_F  11010048     // 32768 u32

// d_ws layout (4-byte units): xx[32768] | idx[32768] | partial[8192] | cnt[1] | list[32768]
#define WS_XX_OFF     0
#define WS_IDX_OFF    32768
#define WS_PART_OFF   65536
#define WS_CNT_OFF    73728
#define WS_LIST_OFF   73729

#define FLT_BIG 3.402823466e+38f
#define W_ACC   0.08192f   // 1.6e-4 (s-domain window) * 512 (acc scale = 1024/2)
#define GCAP    16

typedef __attribute__((address_space(1))) const unsigned int GUI;
typedef __attribute__((address_space(3))) unsigned int LUI;
__device__ __forceinline__ void gload16(const void* g, void* l) {
    __builtin_amdgcn_global_load_lds((GUI*)g, (LUI*)l, 16, 0, 0);
}

// ---------------------------------------------------------------- prep
// xh = fp16(x); eh = fp16(1024*e). 8 f32 -> 8 halves per thread.
__global__ __launch_bounds__(256) void vq_prep(const float* __restrict__ x,
                                               const float* __restrict__ cb,
                                               ushortT* __restrict__ xh,
                                               ushortT* __restrict__ eh) {
    const size_t gid = (size_t)blockIdx.x * 256 + threadIdx.x;
    const size_t off8 = gid * 8;
    const float* src;
    ushortT* dst;
    float sc;
    if (off8 < 16777216UL) { src = x + off8; dst = xh + off8; sc = 1.0f; }
    else { size_t o = off8 - 16777216UL; src = cb + o; dst = eh + o; sc = 1024.0f; }
    float4 v0 = *reinterpret_cast<const float4*>(src);
    float4 v1 = *reinterpret_cast<const float4*>(src + 4);
    union { ushortT s[8]; uint4 v; } u;
    u.s[0] = __half_as_ushort(__float2half(v0.x * sc));
    u.s[1] = __half_as_ushort(__float2half(v0.y * sc));
    u.s[2] = __half_as_ushort(__float2half(v0.z * sc));
    u.s[3] = __half_as_ushort(__float2half(v0.w * sc));
    u.s[4] = __half_as_ushort(__float2half(v1.x * sc));
    u.s[5] = __half_as_ushort(__float2half(v1.y * sc));
    u.s[6] = __half_as_ushort(__float2half(v1.z * sc));
    u.s[7] = __half_as_ushort(__float2half(v1.w * sc));
    *reinterpret_cast<uint4*>(dst) = u.v;
}

// ---------------------------------------------------------------- kernel XX
// xx[n] replicating numpy pairwise_sum exactly (proven in round 3).
__global__ __launch_bounds__(256) void vq_xx_kernel(const float* __restrict__ x,
                                                    float* __restrict__ xx) {
    __shared__ float l[4][512];
    const int wave = threadIdx.x >> 6;
    const int lane = threadIdx.x & 63;
    const int row = blockIdx.x * 4 + wave;
    const float* xr = x + (size_t)row * DIM;
#pragma unroll
    for (int i = 0; i < 2; ++i) {
        float4 v = *reinterpret_cast<const float4*>(xr + lane * 8 + i * 4);
        float4 q = make_float4(v.x * v.x, v.y * v.y, v.z * v.z, v.w * v.w);
        *reinterpret_cast<float4*>(&l[wave][lane * 8 + i * 4]) = q;
    }
    __syncthreads();
    if (lane == 0) {
        float B[4];
#pragma unroll
        for (int q = 0; q < 4; ++q) {
            const float* a = &l[wave][q * 128];
            float r0 = a[0], r1 = a[1], r2 = a[2], r3 = a[3];
            float r4 = a[4], r5 = a[5], r6 = a[6], r7 = a[7];
            for (int i = 8; i < 128; i += 8) {
                r0 += a[i + 0]; r1 += a[i + 1]; r2 += a[i + 2]; r3 += a[i + 3];
                r4 += a[i + 4]; r5 += a[i + 5]; r6 += a[i + 6]; r7 += a[i + 7];
            }
            B[q] = ((r0 + r1) + (r2 + r3)) + ((r4 + r5) + (r6 + r7));
        }
        xx[row] = (B[0] + B[1]) + (B[2] + B[3]);
    }
}

// ---------------------------------------------------------------- kernel M
// fp16 MFMA candidate pass. BM=128 x BN=256, BK=64, 8 waves (2x4), 4x4 frags.
// In-loop epilogue: register-only per-lane top-1(+tag) / top-2-value MAX of raw
// acc (argmin s == argmax acc per row). Candidate extraction once at the end.
#define BM 128
#define BN 256
#define BKH 64

__global__ __launch_bounds__(512, 2) void vq_margmin(
    const ushortT* __restrict__ xh, const ushortT* __restrict__ eh,
    unsigned* __restrict__ gCode, unsigned* __restrict__ gCnt,
    int* __restrict__ fixcnt, int* __restrict__ fixlist) {
    __shared__ ushortT As[BM * BKH];      // 16 KB
    __shared__ ushortT Bs[BN * BKH];      // 32 KB
    __shared__ float   v1L[BM][4];        // 2 KB  per-(row,wave) max
    __shared__ float   rowThr[BM];
    __shared__ unsigned candCnt[BM];
    __shared__ ushortT candList[BM][GCAP];// 4 KB
    __shared__ int     flagL[BM];

    const int t = threadIdx.x;
    const int l = t & 63;
    const int wid = t >> 6;
    const int wm = wid >> 2;      // 0..1 : 64-row region
    const int wn = wid & 3;       // 0..3 : 64-col region
    const int lr = l & 15;
    const int lg = l >> 4;
    const int rowBase = blockIdx.x * BM;

    if (t < BM) { candCnt[t] = 0u; flagL[t] = 0; }

    float v1[4][4], v2m[4][4];
    int i1[4][4];
#pragma unroll
    for (int mf = 0; mf < 4; ++mf)
#pragma unroll
        for (int rr = 0; rr < 4; ++rr) {
            v1[mf][rr] = -FLT_BIG; v2m[mf][rr] = -FLT_BIG; i1[mf][rr] = 0;
        }

    for (int k0t = 0; k0t < K_CODES / BN; ++k0t) {
        const int k0 = k0t * BN;
        f32x4 acc[4][4];
#pragma unroll
        for (int mf = 0; mf < 4; ++mf)
#pragma unroll
            for (int nf = 0; nf < 4; ++nf)
                acc[mf][nf] = (f32x4){0.f, 0.f, 0.f, 0.f};

        for (int kt = 0; kt < DIM; kt += BKH) {
            __syncthreads();   // previous sub-tile reads done before overwrite
            // stage A: 1024 16B chunks (swizzled source, linear LDS dest)
#pragma unroll
            for (int i = 0; i < 2; ++i) {
                int f = t + i * 512;
                int r = f >> 3, g = f & 7;
                int gs = g ^ (r & 7);
                gload16(xh + (size_t)(rowBase + r) * DIM + kt + gs * 8, As + f * 8);
            }
            // stage B: 2048 chunks
#pragma unroll
            for (int i = 0; i < 4; ++i) {
                int f = t + i * 512;
                int r = f >> 3, g = f & 7;
                int gs = g ^ (r & 7);
                gload16(eh + (size_t)(k0 + r) * DIM + kt + gs * 8, Bs + f * 8);
            }
            __syncthreads();
#pragma unroll
            for (int ks8 = 0; ks8 < 8; ks8 += 4) {   // two K=32 substeps
                half8 a[4], b[4];
#pragma unroll
                for (int mf = 0; mf < 4; ++mf) {
                    int row = wm * 64 + mf * 16 + lr;
                    int pg = (ks8 + lg) ^ (row & 7);
                    a[mf] = *reinterpret_cast<const half8*>(As + row * BKH + pg * 8);
                }
#pragma unroll
                for (int nf = 0; nf < 4; ++nf) {
                    int col = wn * 64 + nf * 16 + lr;
                    int pg = (ks8 + lg) ^ (col & 7);
                    b[nf] = *reinterpret_cast<const half8*>(Bs + col * BKH + pg * 8);
                }
#pragma unroll
                for (int mf = 0; mf < 4; ++mf)
#pragma unroll
                    for (int nf = 0; nf < 4; ++nf)
                        acc[mf][nf] = __builtin_amdgcn_mfma_f32_16x16x32_f16(
                            a[mf], b[nf], acc[mf][nf], 0, 0, 0);
            }
        }
        // register-only epilogue: per-lane running top-1(+tag) and top-2 value
#pragma unroll
        for (int mf = 0; mf < 4; ++mf) {
#pragma unroll
            for (int nf = 0; nf < 4; ++nf) {
                const int tag = (k0t << 2) | nf;
#pragma unroll
                for (int rr = 0; rr < 4; ++rr) {
                    float s = acc[mf][nf][rr];
                    bool g = s > v1[mf][rr];
                    v2m[mf][rr] = fmaxf(v2m[mf][rr], fminf(v1[mf][rr], s));
                    v1[mf][rr] = fmaxf(v1[mf][rr], s);
                    i1[mf][rr] = g ? tag : i1[mf][rr];
                }
            }
        }
    }

    // ---- Phase A: in-wave (16 lr lanes) max per row, one writer per group
    __syncthreads();
#pragma unroll
    for (int mf = 0; mf < 4; ++mf)
#pragma unroll
        for (int rr = 0; rr < 4; ++rr) {
            float v = v1[mf][rr];
            v = fmaxf(v, __shfl_xor(v, 1));
            v = fmaxf(v, __shfl_xor(v, 2));
            v = fmaxf(v, __shfl_xor(v, 4));
            v = fmaxf(v, __shfl_xor(v, 8));
            if (lr == 0) v1L[wm * 64 + mf * 16 + lg * 4 + rr][wn] = v;
        }
    __syncthreads();
    // ---- Phase B: per-row threshold
    if (t < BM) {
        float m = fmaxf(fmaxf(v1L[t][0], v1L[t][1]), fmaxf(v1L[t][2], v1L[t][3]));
        rowThr[t] = m - W_ACC;
    }
    __syncthreads();
    // ---- Phase C: lane-level candidate push + hidden-candidate flag
#pragma unroll
    for (int mf = 0; mf < 4; ++mf)
#pragma unroll
        for (int rr = 0; rr < 4; ++rr) {
            const int row = wm * 64 + mf * 16 + lg * 4 + rr;
            const float thr = rowThr[row];
            if (v1[mf][rr] >= thr) {
                unsigned pos = atomicAdd(&candCnt[row], 1u);
                int tg = i1[mf][rr];
                int code = ((tg >> 2) << 8) | (wn << 6) | ((tg & 3) << 4) | lr;
                if (pos < GCAP) candList[row][pos] = (ushortT)code;
                else flagL[row] = 1;
            }
            if (v2m[mf][rr] >= thr) flagL[row] = 1;  // 2 cands on one lane: rescue
        }
    __syncthreads();
    // ---- Phase D: emit
    if (t < BM) {
        const int grow = rowBase + t;
        unsigned cc = candCnt[t];
        if (flagL[t] || cc > GCAP) {
            gCnt[grow] = 0xFFFFFFFFu;
            int pos = atomicAdd(fixcnt, 1);
            fixlist[pos] = grow;
        } else {
            for (unsigned j = 0; j < cc; ++j)
                gCode[(size_t)grow * GCAP + j] = candList[t][j];
            gCnt[grow] = cc;
        }
    }
}

// ---------------------------------------------------------------- refine
// fp64-exact dots for each candidate, quantized compare s=fl32(xx-(f32)(2*dot)),
// first-index tie-break. One wave per row.
__global__ __launch_bounds__(256) void vq_refine(
    const float* __restrict__ x, const float* __restrict__ cb,
    const float* __restrict__ xx, const unsigned* __restrict__ gCode,
    const unsigned* __restrict__ gCnt, float* __restrict__ outIdxF,
    int* __restrict__ idxI) {
    const int wave = threadIdx.x >> 6;
    const int lane = threadIdx.x & 63;
    const int row = blockIdx.x * 4 + wave;
    const unsigned cc = gCnt[row];
    if (cc == 0xFFFFFFFFu) return;   // full fixup handles this row
    const float* xr = x + (size_t)row * DIM;
    float4 xa = *reinterpret_cast<const float4*>(xr + lane * 8);
    float4 xb = *reinterpret_cast<const float4*>(xr + lane * 8 + 4);
    const float xxrow = xx[row];
    float best = FLT_BIG;
    int bi = 0x7fffffff;
    for (unsigned c = 0; c < cc; ++c) {
        int code = (int)gCode[(size_t)row * GCAP + c];
        const float* er = cb + (size_t)code * DIM;
        float4 ea = *reinterpret_cast<const float4*>(er + lane * 8);
        float4 eb = *reinterpret_cast<const float4*>(er + lane * 8 + 4);
        double p = (double)xa.x * ea.x + (double)xa.y * ea.y
                 + (double)xa.z * ea.z + (double)xa.w * ea.w
                 + (double)xb.x * eb.x + (double)xb.y * eb.y
                 + (double)xb.z * eb.z + (double)xb.w * eb.w;
#pragma unroll
        for (int off = 1; off < 64; off <<= 1) p += __shfl_xor(p, off);
        float sc = xxrow - (float)(2.0 * p);
        if (sc < best || (sc == best && code < bi)) { best = sc; bi = code; }
    }
    if (lane == 0) { idxI[row] = bi; outIdxF[row] = (float)bi; }
}

// ---------------------------------------------------------------- fixup
// Full 8192-code re-rank for flagged rows (expected ~50). Round-3 proven.
__global__ __launch_bounds__(256) void vq_fixup_kernel(
    const float* __restrict__ x, const float* __restrict__ cb,
    const float* __restrict__ xx, const int* __restrict__ cnt,
    const int* __restrict__ list, float* __restrict__ outIdxF,
    int* __restrict__ idxI) {
    __shared__ float xr[DIM];
    __shared__ float rv[256];
    __shared__ int ri[256];
    const int t = threadIdx.x;
    const int nflag = *cnt;
    for (int it = blockIdx.x; it < nflag; it += gridDim.x) {
        const int row = list[it];
        __syncthreads();
        xr[t] = x[(size_t)row * DIM + t];
        xr[t + 256] = x[(size_t)row * DIM + 256 + t];
        __syncthreads();
        const float xxrow = xx[row];
        float best = FLT_BIG;
        int bi = 0x7fffffff;
        for (int k = t; k < K_CODES; k += 256) {
            const float* er = cb + (size_t)k * DIM;
            double xe0 = 0.0, xe1 = 0.0, xe2d = 0.0, xe3 = 0.0;
            for (int d = 0; d < DIM; d += 4) {
                float4 ev = *reinterpret_cast<const float4*>(er + d);
                xe0 = fma((double)xr[d + 0], (double)ev.x, xe0);
                xe1 = fma((double)xr[d + 1], (double)ev.y, xe1);
                xe2d = fma((double)xr[d + 2], (double)ev.z, xe2d);
                xe3 = fma((double)xr[d + 3], (double)ev.w, xe3);
            }
            double xe = (xe0 + xe1) + (xe2d + xe3);
            float c = (float)(2.0 * xe);
            float s = xxrow - c;
            if (s < best) { best = s; bi = k; }
        }
        rv[t] = best; ri[t] = bi;
        __syncthreads();
        for (int off = 128; off > 0; off >>= 1) {
            if (t < off) {
                float ov = rv[t + off]; int oi = ri[t + off];
                if (ov < rv[t] || (ov == rv[t] && oi < ri[t])) { rv[t] = ov; ri[t] = oi; }
            }
            __syncthreads();
        }
        if (t == 0) {
            idxI[row] = ri[0];
            outIdxF[row] = (float)ri[0];
        }
    }
}

// ---------------------------------------------------------------- gather
__global__ __launch_bounds__(256) void vq_gather_kernel(
    const float* __restrict__ x, const float* __restrict__ cb,
    const int* __restrict__ idxI, float* __restrict__ outQ,
    float* __restrict__ partial) {
    const int wave = threadIdx.x >> 6;
    const int lane = threadIdx.x & 63;
    const int row = blockIdx.x * 4 + wave;
    const int code = idxI[row];
    const float* xr = x + (size_t)row * DIM;
    const float* er = cb + (size_t)code * DIM;
    float* qr = outQ + (size_t)row * DIM;
    float s = 0.f;
#pragma unroll
    for (int i = 0; i < 2; ++i) {
        int d = lane * 8 + i * 4;
        float4 xv = *reinterpret_cast<const float4*>(xr + d);
        float4 ev = *reinterpret_cast<const float4*>(er + d);
        float4 dv = make_float4(ev.x - xv.x, ev.y - xv.y, ev.z - xv.z, ev.w - xv.w);
        *reinterpret_cast<float4*>(qr + d) = ev;
        s += dv.x * dv.x + dv.y * dv.y + dv.z * dv.z + dv.w * dv.w;
    }
#pragma unroll
    for (int off = 32; off > 0; off >>= 1) s += __shfl_xor(s, off);
    __shared__ float ws4[4];
    if (lane == 0) ws4[wave] = s;
    __syncthreads();
    if (threadIdx.x == 0)
        partial[blockIdx.x] = (ws4[0] + ws4[1]) + (ws4[2] + ws4[3]);
}

// ---------------------------------------------------------------- loss
__global__ __launch_bounds__(256) void vq_loss_kernel(const float* __restrict__ partial,
                                                      float* __restrict__ outLoss) {
    float s = 0.f;
    for (int i = threadIdx.x; i < 8192; i += 256) s += partial[i];
    __shared__ float sm[256];
    sm[threadIdx.x] = s;
    __syncthreads();
    for (int off = 128; off > 0; off >>= 1) {
        if (threadIdx.x < off) sm[threadIdx.x] += sm[threadIdx.x + off];
        __syncthreads();
    }
    if (threadIdx.x == 0)
        outLoss[0] = sm[0] * (1.0f + BETA) / 16777216.0f;
}

// ---------------------------------------------------------------- launch
extern "C" void kernel_launch(void* const* d_in, const int* in_sizes, int n_in,
                              void* d_out, int out_size, void* d_ws, size_t ws_size,
                              hipStream_t stream) {
    const float* x = (const float*)d_in[0];   // [32768, 512]
    const float* cb = (const float*)d_in[1];  // [8192, 512]
    float* out = (float*)d_out;

    // d_out scratch (rewritten by gather at the end)
    ushortT* xh = (ushortT*)out;
    ushortT* eh = (ushortT*)(out + SC_EH_F);
    unsigned* gCode = (unsigned*)(out + SC_GCODE_F);
    unsigned* gCnt = (unsigned*)(out + SC_GCNT_F);

    float* xx = (float*)d_ws + WS_XX_OFF;
    int* idxI = (int*)d_ws + WS_IDX_OFF;
    float* partial = (float*)d_ws + WS_PART_OFF;
    int* fixcnt = (int*)d_ws + WS_CNT_OFF;
    int* fixlist = (int*)d_ws + WS_LIST_OFF;

    hipMemsetAsync(fixcnt, 0, sizeof(int), stream);
    hipLaunchKernelGGL(vq_prep, dim3(10240), dim3(256), 0, stream, x, cb, xh, eh);
    hipLaunchKernelGGL(vq_xx_kernel, dim3(N_ROWS / 4), dim3(256), 0, stream, x, xx);
    hipLaunchKernelGGL(vq_margmin, dim3(N_ROWS / BM), dim3(512), 0, stream,
                       xh, eh, gCode, gCnt, fixcnt, fixlist);
    hipLaunchKernelGGL(vq_refine, dim3(N_ROWS / 4), dim3(256), 0, stream,
                       x, cb, xx, gCode, gCnt, out + IDX_OFF, idxI);
    hipLaunchKernelGGL(vq_fixup_kernel, dim3(256), dim3(256), 0, stream,
                       x, cb, xx, fixcnt, fixlist, out + IDX_OFF, idxI);
    hipLaunchKernelGGL(vq_gather_kernel, dim3(N_ROWS / 4), dim3(256), 0, stream,
                       x, cb, idxI, out, partial);
    hipLaunchKernelGGL(vq_loss_kernel, dim3(1), dim3(256), 0, stream,
                       partial, out + LOSS_OFF);
}

// Round 6
// 558.432 us; speedup vs baseline: 1.8701x; 1.8701x over previous
//
#include <hip/hip_runtime.h>
#include <hip/hip_bf16.h>
#include <hip/hip_fp16.h>

typedef unsigned short ushortT;
typedef _Float16 half8 __attribute__((ext_vector_type(8)));
typedef float f32x4 __attribute__((ext_vector_type(4)));

#define N_ROWS   32768
#define DIM      512
#define K_CODES  8192
#define BETA     0.01f

// d_out layout (floats): [quantized 16777216][loss 1][indices-as-float 32768]
#define LOSS_OFF 16777216
#define IDX_OFF  16777217

// d_out-as-scratch (floats offsets). Legal: vq_gather rewrites [0,16.7M) last.
#define SC_XH_F    0            // 32768*512 halves = 8M floats
#define SC_EH_F    8388608      // 8192*512 halves  = 2M floats
#define SC_GCODE_F 10485760     // 32768*16 u32
#define SC_GCNT_F  11010048     // 32768 u32

// d_ws layout (4-byte units): xx[32768] | idx[32768] | partial[8192] | cnt[1] | list[32768]
#define WS_XX_OFF     0
#define WS_IDX_OFF    32768
#define WS_PART_OFF   65536
#define WS_CNT_OFF    73728
#define WS_LIST_OFF   73729

#define FLT_BIG 3.402823466e+38f
#define W_ACC   0.08192f   // 1.6e-4 (s-domain window) * 512 (acc scale = 1024/2)
#define GCAP    16

typedef __attribute__((address_space(1))) const unsigned int GUI;
typedef __attribute__((address_space(3))) unsigned int LUI;
__device__ __forceinline__ void gload16(const void* g, void* l) {
    __builtin_amdgcn_global_load_lds((GUI*)g, (LUI*)l, 16, 0, 0);
}

// ---------------------------------------------------------------- prep
// xh = fp16(x); eh = fp16(1024*e). 8 f32 -> 8 halves per thread.
__global__ __launch_bounds__(256) void vq_prep(const float* __restrict__ x,
                                               const float* __restrict__ cb,
                                               ushortT* __restrict__ xh,
                                               ushortT* __restrict__ eh) {
    const size_t gid = (size_t)blockIdx.x * 256 + threadIdx.x;
    const size_t off8 = gid * 8;
    const float* src;
    ushortT* dst;
    float sc;
    if (off8 < 16777216UL) { src = x + off8; dst = xh + off8; sc = 1.0f; }
    else { size_t o = off8 - 16777216UL; src = cb + o; dst = eh + o; sc = 1024.0f; }
    float4 v0 = *reinterpret_cast<const float4*>(src);
    float4 v1 = *reinterpret_cast<const float4*>(src + 4);
    union { ushortT s[8]; uint4 v; } u;
    u.s[0] = __half_as_ushort(__float2half(v0.x * sc));
    u.s[1] = __half_as_ushort(__float2half(v0.y * sc));
    u.s[2] = __half_as_ushort(__float2half(v0.z * sc));
    u.s[3] = __half_as_ushort(__float2half(v0.w * sc));
    u.s[4] = __half_as_ushort(__float2half(v1.x * sc));
    u.s[5] = __half_as_ushort(__float2half(v1.y * sc));
    u.s[6] = __half_as_ushort(__float2half(v1.z * sc));
    u.s[7] = __half_as_ushort(__float2half(v1.w * sc));
    *reinterpret_cast<uint4*>(dst) = u.v;
}

// ---------------------------------------------------------------- kernel XX
// xx[n] replicating numpy pairwise_sum exactly (proven in round 3).
__global__ __launch_bounds__(256) void vq_xx_kernel(const float* __restrict__ x,
                                                    float* __restrict__ xx) {
    __shared__ float l[4][512];
    const int wave = threadIdx.x >> 6;
    const int lane = threadIdx.x & 63;
    const int row = blockIdx.x * 4 + wave;
    const float* xr = x + (size_t)row * DIM;
#pragma unroll
    for (int i = 0; i < 2; ++i) {
        float4 v = *reinterpret_cast<const float4*>(xr + lane * 8 + i * 4);
        float4 q = make_float4(v.x * v.x, v.y * v.y, v.z * v.z, v.w * v.w);
        *reinterpret_cast<float4*>(&l[wave][lane * 8 + i * 4]) = q;
    }
    __syncthreads();
    if (lane == 0) {
        float B[4];
#pragma unroll
        for (int q = 0; q < 4; ++q) {
            const float* a = &l[wave][q * 128];
            float r0 = a[0], r1 = a[1], r2 = a[2], r3 = a[3];
            float r4 = a[4], r5 = a[5], r6 = a[6], r7 = a[7];
            for (int i = 8; i < 128; i += 8) {
                r0 += a[i + 0]; r1 += a[i + 1]; r2 += a[i + 2]; r3 += a[i + 3];
                r4 += a[i + 4]; r5 += a[i + 5]; r6 += a[i + 6]; r7 += a[i + 7];
            }
            B[q] = ((r0 + r1) + (r2 + r3)) + ((r4 + r5) + (r6 + r7));
        }
        xx[row] = (B[0] + B[1]) + (B[2] + B[3]);
    }
}

// ---------------------------------------------------------------- kernel M
// fp16 MFMA candidate pass. BM=128 x BN=256, BK=64, 8 waves (2x4), 4x4 frags.
// Double-buffered LDS (T3-minimum 2-phase pipeline, 1 barrier/step).
// Register-only per-lane top-2(+tags)/top-3-value MAX of raw acc
// (argmin s == argmax acc per row). Candidate extraction once at the end.
#define BM 128
#define BN 256
#define BKH 64
#define NSTEP 256   // (K_CODES/BN) * (DIM/BKH) = 32 * 8

__global__ __launch_bounds__(512, 1) void vq_margmin(
    const ushortT* __restrict__ xh, const ushortT* __restrict__ eh,
    unsigned* __restrict__ gCode, unsigned* __restrict__ gCnt,
    int* __restrict__ fixcnt, int* __restrict__ fixlist) {
    __shared__ ushortT As[2][BM * BKH];   // 32 KB
    __shared__ ushortT Bs[2][BN * BKH];   // 64 KB
    __shared__ float   v1L[BM][4];
    __shared__ float   rowThr[BM];
    __shared__ unsigned candCnt[BM];
    __shared__ ushortT candList[BM][GCAP];
    __shared__ int     flagL[BM];

    const int t = threadIdx.x;
    const int l = t & 63;
    const int wid = t >> 6;
    const int wm = wid >> 2;      // 0..1 : 64-row region
    const int wn = wid & 3;       // 0..3 : 64-col region
    const int lr = l & 15;
    const int lg = l >> 4;
    const int rowBase = blockIdx.x * BM;

    if (t < BM) { candCnt[t] = 0u; flagL[t] = 0; }

    float v1[4][4], v2m[4][4], v3m[4][4];
    int i1[4][4], i2[4][4];
#pragma unroll
    for (int mf = 0; mf < 4; ++mf)
#pragma unroll
        for (int rr = 0; rr < 4; ++rr) {
            v1[mf][rr] = -FLT_BIG; v2m[mf][rr] = -FLT_BIG; v3m[mf][rr] = -FLT_BIG;
            i1[mf][rr] = 0; i2[mf][rr] = 0;
        }

#define STAGE(stp, b) do {                                                     \
    const int k0_ = ((stp) >> 3) * BN;                                         \
    const int kt_ = ((stp) & 7) * BKH;                                         \
    _Pragma("unroll")                                                          \
    for (int i_ = 0; i_ < 2; ++i_) {                                           \
        int f_ = t + i_ * 512;                                                 \
        int r_ = f_ >> 3, g_ = f_ & 7;                                         \
        int gs_ = g_ ^ (r_ & 7);                                               \
        gload16(xh + (size_t)(rowBase + r_) * DIM + kt_ + gs_ * 8,             \
                &As[b][f_ * 8]);                                               \
    }                                                                          \
    _Pragma("unroll")                                                          \
    for (int i_ = 0; i_ < 4; ++i_) {                                           \
        int f_ = t + i_ * 512;                                                 \
        int r_ = f_ >> 3, g_ = f_ & 7;                                         \
        int gs_ = g_ ^ (r_ & 7);                                               \
        gload16(eh + (size_t)(k0_ + r_) * DIM + kt_ + gs_ * 8,                 \
                &Bs[b][f_ * 8]);                                               \
    }                                                                          \
} while (0)

    // prologue: stage step 0 into buffer 0 (barrier drains vmcnt)
    STAGE(0, 0);
    __syncthreads();

    int cur = 0;
    f32x4 acc[4][4];
    for (int step = 0; step < NSTEP; ++step) {
        const int k0t = step >> 3;
        if ((step & 7) == 0) {
#pragma unroll
            for (int mf = 0; mf < 4; ++mf)
#pragma unroll
                for (int nf = 0; nf < 4; ++nf)
                    acc[mf][nf] = (f32x4){0.f, 0.f, 0.f, 0.f};
        }
        // issue next-step staging into the other buffer (in flight during MFMA)
        if (step + 1 < NSTEP) STAGE(step + 1, cur ^ 1);
        // compute current buffer
#pragma unroll
        for (int ks8 = 0; ks8 < 8; ks8 += 4) {   // two K=32 substeps
            half8 a[4], b[4];
#pragma unroll
            for (int mf = 0; mf < 4; ++mf) {
                int row = wm * 64 + mf * 16 + lr;
                int pg = (ks8 + lg) ^ (row & 7);
                a[mf] = *reinterpret_cast<const half8*>(&As[cur][row * BKH + pg * 8]);
            }
#pragma unroll
            for (int nf = 0; nf < 4; ++nf) {
                int col = wn * 64 + nf * 16 + lr;
                int pg = (ks8 + lg) ^ (col & 7);
                b[nf] = *reinterpret_cast<const half8*>(&Bs[cur][col * BKH + pg * 8]);
            }
#pragma unroll
            for (int mf = 0; mf < 4; ++mf)
#pragma unroll
                for (int nf = 0; nf < 4; ++nf)
                    acc[mf][nf] = __builtin_amdgcn_mfma_f32_16x16x32_f16(
                        a[mf], b[nf], acc[mf][nf], 0, 0, 0);
        }
        // per-k0t register epilogue: running top-2 (with tags) + top-3 value
        if ((step & 7) == 7) {
#pragma unroll
            for (int mf = 0; mf < 4; ++mf) {
#pragma unroll
                for (int nf = 0; nf < 4; ++nf) {
                    const int tag = (k0t << 2) | nf;
#pragma unroll
                    for (int rr = 0; rr < 4; ++rr) {
                        float s = acc[mf][nf][rr];
                        bool g1 = s > v1[mf][rr];
                        bool g2 = s > v2m[mf][rr];
                        bool g3 = s > v3m[mf][rr];
                        v3m[mf][rr] = g2 ? v2m[mf][rr] : (g3 ? s : v3m[mf][rr]);
                        i2[mf][rr]  = g1 ? i1[mf][rr]  : (g2 ? tag : i2[mf][rr]);
                        v2m[mf][rr] = g1 ? v1[mf][rr]  : (g2 ? s : v2m[mf][rr]);
                        i1[mf][rr]  = g1 ? tag : i1[mf][rr];
                        v1[mf][rr]  = g1 ? s   : v1[mf][rr];
                    }
                }
            }
        }
        // single barrier per step: drains staging (vmcnt) + synchronizes reuse
        __syncthreads();
        cur ^= 1;
    }

    // ---- Phase A: in-wave (16 lr lanes) max per row, one writer per group
#pragma unroll
    for (int mf = 0; mf < 4; ++mf)
#pragma unroll
        for (int rr = 0; rr < 4; ++rr) {
            float v = v1[mf][rr];
            v = fmaxf(v, __shfl_xor(v, 1));
            v = fmaxf(v, __shfl_xor(v, 2));
            v = fmaxf(v, __shfl_xor(v, 4));
            v = fmaxf(v, __shfl_xor(v, 8));
            if (lr == 0) v1L[wm * 64 + mf * 16 + lg * 4 + rr][wn] = v;
        }
    __syncthreads();
    // ---- Phase B: per-row threshold
    if (t < BM) {
        float m = fmaxf(fmaxf(v1L[t][0], v1L[t][1]), fmaxf(v1L[t][2], v1L[t][3]));
        rowThr[t] = m - W_ACC;
    }
    __syncthreads();
    // ---- Phase C: lane-level candidate pushes (top-2 tags) + 3rd-value flag
#pragma unroll
    for (int mf = 0; mf < 4; ++mf)
#pragma unroll
        for (int rr = 0; rr < 4; ++rr) {
            const int row = wm * 64 + mf * 16 + lg * 4 + rr;
            const float thr = rowThr[row];
            if (v1[mf][rr] >= thr) {
                unsigned pos = atomicAdd(&candCnt[row], 1u);
                int tg = i1[mf][rr];
                int code = ((tg >> 2) << 8) | (wn << 6) | ((tg & 3) << 4) | lr;
                if (pos < GCAP) candList[row][pos] = (ushortT)code;
                else flagL[row] = 1;
            }
            if (v2m[mf][rr] >= thr) {
                unsigned pos = atomicAdd(&candCnt[row], 1u);
                int tg = i2[mf][rr];
                int code = ((tg >> 2) << 8) | (wn << 6) | ((tg & 3) << 4) | lr;
                if (pos < GCAP) candList[row][pos] = (ushortT)code;
                else flagL[row] = 1;
            }
            if (v3m[mf][rr] >= thr) flagL[row] = 1;  // 3 cands on one lane: rescue
        }
    __syncthreads();
    // ---- Phase D: emit
    if (t < BM) {
        const int grow = rowBase + t;
        unsigned cc = candCnt[t];
        if (flagL[t] || cc > GCAP) {
            gCnt[grow] = 0xFFFFFFFFu;
            int pos = atomicAdd(fixcnt, 1);
            fixlist[pos] = grow;
        } else {
            for (unsigned j = 0; j < cc; ++j)
                gCode[(size_t)grow * GCAP + j] = candList[t][j];
            gCnt[grow] = cc;
        }
    }
#undef STAGE
}

// ---------------------------------------------------------------- refine
// fp64-exact dots for each candidate, quantized compare s=fl32(xx-(f32)(2*dot)),
// first-index tie-break. One wave per row.
__global__ __launch_bounds__(256) void vq_refine(
    const float* __restrict__ x, const float* __restrict__ cb,
    const float* __restrict__ xx, const unsigned* __restrict__ gCode,
    const unsigned* __restrict__ gCnt, float* __restrict__ outIdxF,
    int* __restrict__ idxI) {
    const int wave = threadIdx.x >> 6;
    const int lane = threadIdx.x & 63;
    const int row = blockIdx.x * 4 + wave;
    const unsigned cc = gCnt[row];
    if (cc == 0xFFFFFFFFu) return;   // full fixup handles this row
    const float* xr = x + (size_t)row * DIM;
    float4 xa = *reinterpret_cast<const float4*>(xr + lane * 8);
    float4 xb = *reinterpret_cast<const float4*>(xr + lane * 8 + 4);
    const float xxrow = xx[row];
    float best = FLT_BIG;
    int bi = 0x7fffffff;
    for (unsigned c = 0; c < cc; ++c) {
        int code = (int)gCode[(size_t)row * GCAP + c];
        const float* er = cb + (size_t)code * DIM;
        float4 ea = *reinterpret_cast<const float4*>(er + lane * 8);
        float4 eb = *reinterpret_cast<const float4*>(er + lane * 8 + 4);
        double p = (double)xa.x * ea.x + (double)xa.y * ea.y
                 + (double)xa.z * ea.z + (double)xa.w * ea.w
                 + (double)xb.x * eb.x + (double)xb.y * eb.y
                 + (double)xb.z * eb.z + (double)xb.w * eb.w;
#pragma unroll
        for (int off = 1; off < 64; off <<= 1) p += __shfl_xor(p, off);
        float sc = xxrow - (float)(2.0 * p);
        if (sc < best || (sc == best && code < bi)) { best = sc; bi = code; }
    }
    if (lane == 0) { idxI[row] = bi; outIdxF[row] = (float)bi; }
}

// ---------------------------------------------------------------- fixup
// Full 8192-code re-rank for flagged rows (expected ~0). Round-3 proven.
__global__ __launch_bounds__(256) void vq_fixup_kernel(
    const float* __restrict__ x, const float* __restrict__ cb,
    const float* __restrict__ xx, const int* __restrict__ cnt,
    const int* __restrict__ list, float* __restrict__ outIdxF,
    int* __restrict__ idxI) {
    __shared__ float xr[DIM];
    __shared__ float rv[256];
    __shared__ int ri[256];
    const int t = threadIdx.x;
    const int nflag = *cnt;
    for (int it = blockIdx.x; it < nflag; it += gridDim.x) {
        const int row = list[it];
        __syncthreads();
        xr[t] = x[(size_t)row * DIM + t];
        xr[t + 256] = x[(size_t)row * DIM + 256 + t];
        __syncthreads();
        const float xxrow = xx[row];
        float best = FLT_BIG;
        int bi = 0x7fffffff;
        for (int k = t; k < K_CODES; k += 256) {
            const float* er = cb + (size_t)k * DIM;
            double xe0 = 0.0, xe1 = 0.0, xe2d = 0.0, xe3 = 0.0;
            for (int d = 0; d < DIM; d += 4) {
                float4 ev = *reinterpret_cast<const float4*>(er + d);
                xe0 = fma((double)xr[d + 0], (double)ev.x, xe0);
                xe1 = fma((double)xr[d + 1], (double)ev.y, xe1);
                xe2d = fma((double)xr[d + 2], (double)ev.z, xe2d);
                xe3 = fma((double)xr[d + 3], (double)ev.w, xe3);
            }
            double xe = (xe0 + xe1) + (xe2d + xe3);
            float c = (float)(2.0 * xe);
            float s = xxrow - c;
            if (s < best) { best = s; bi = k; }
        }
        rv[t] = best; ri[t] = bi;
        __syncthreads();
        for (int off = 128; off > 0; off >>= 1) {
            if (t < off) {
                float ov = rv[t + off]; int oi = ri[t + off];
                if (ov < rv[t] || (ov == rv[t] && oi < ri[t])) { rv[t] = ov; ri[t] = oi; }
            }
            __syncthreads();
        }
        if (t == 0) {
            idxI[row] = ri[0];
            outIdxF[row] = (float)ri[0];
        }
    }
}

// ---------------------------------------------------------------- gather
__global__ __launch_bounds__(256) void vq_gather_kernel(
    const float* __restrict__ x, const float* __restrict__ cb,
    const int* __restrict__ idxI, float* __restrict__ outQ,
    float* __restrict__ partial) {
    const int wave = threadIdx.x >> 6;
    const int lane = threadIdx.x & 63;
    const int row = blockIdx.x * 4 + wave;
    const int code = idxI[row];
    const float* xr = x + (size_t)row * DIM;
    const float* er = cb + (size_t)code * DIM;
    float* qr = outQ + (size_t)row * DIM;
    float s = 0.f;
#pragma unroll
    for (int i = 0; i < 2; ++i) {
        int d = lane * 8 + i * 4;
        float4 xv = *reinterpret_cast<const float4*>(xr + d);
        float4 ev = *reinterpret_cast<const float4*>(er + d);
        float4 dv = make_float4(ev.x - xv.x, ev.y - xv.y, ev.z - xv.z, ev.w - xv.w);
        *reinterpret_cast<float4*>(qr + d) = ev;
        s += dv.x * dv.x + dv.y * dv.y + dv.z * dv.z + dv.w * dv.w;
    }
#pragma unroll
    for (int off = 32; off > 0; off >>= 1) s += __shfl_xor(s, off);
    __shared__ float ws4[4];
    if (lane == 0) ws4[wave] = s;
    __syncthreads();
    if (threadIdx.x == 0)
        partial[blockIdx.x] = (ws4[0] + ws4[1]) + (ws4[2] + ws4[3]);
}

// ---------------------------------------------------------------- loss
__global__ __launch_bounds__(256) void vq_loss_kernel(const float* __restrict__ partial,
                                                      float* __restrict__ outLoss) {
    float s = 0.f;
    for (int i = threadIdx.x; i < 8192; i += 256) s += partial[i];
    __shared__ float sm[256];
    sm[threadIdx.x] = s;
    __syncthreads();
    for (int off = 128; off > 0; off >>= 1) {
        if (threadIdx.x < off) sm[threadIdx.x] += sm[threadIdx.x + off];
        __syncthreads();
    }
    if (threadIdx.x == 0)
        outLoss[0] = sm[0] * (1.0f + BETA) / 16777216.0f;
}

// ---------------------------------------------------------------- launch
extern "C" void kernel_launch(void* const* d_in, const int* in_sizes, int n_in,
                              void* d_out, int out_size, void* d_ws, size_t ws_size,
                              hipStream_t stream) {
    const float* x = (const float*)d_in[0];   // [32768, 512]
    const float* cb = (const float*)d_in[1];  // [8192, 512]
    float* out = (float*)d_out;

    // d_out scratch (rewritten by gather at the end)
    ushortT* xh = (ushortT*)out;
    ushortT* eh = (ushortT*)(out + SC_EH_F);
    unsigned* gCode = (unsigned*)(out + SC_GCODE_F);
    unsigned* gCnt = (unsigned*)(out + SC_GCNT_F);

    float* xx = (float*)d_ws + WS_XX_OFF;
    int* idxI = (int*)d_ws + WS_IDX_OFF;
    float* partial = (float*)d_ws + WS_PART_OFF;
    int* fixcnt = (int*)d_ws + WS_CNT_OFF;
    int* fixlist = (int*)d_ws + WS_LIST_OFF;

    hipMemsetAsync(fixcnt, 0, sizeof(int), stream);
    hipLaunchKernelGGL(vq_prep, dim3(10240), dim3(256), 0, stream, x, cb, xh, eh);
    hipLaunchKernelGGL(vq_xx_kernel, dim3(N_ROWS / 4), dim3(256), 0, stream, x, xx);
    hipLaunchKernelGGL(vq_margmin, dim3(N_ROWS / BM), dim3(512), 0, stream,
                       xh, eh, gCode, gCnt, fixcnt, fixlist);
    hipLaunchKernelGGL(vq_refine, dim3(N_ROWS / 4), dim3(256), 0, stream,
                       x, cb, xx, gCode, gCnt, out + IDX_OFF, idxI);
    hipLaunchKernelGGL(vq_fixup_kernel, dim3(256), dim3(256), 0, stream,
                       x, cb, xx, fixcnt, fixlist, out + IDX_OFF, idxI);
    hipLaunchKernelGGL(vq_gather_kernel, dim3(N_ROWS / 4), dim3(256), 0, stream,
                       x, cb, idxI, out, partial);
    hipLaunchKernelGGL(vq_loss_kernel, dim3(1), dim3(256), 0, stream,
                       partial, out + LOSS_OFF);
}